// Round 7
// baseline (118.828 us; speedup 1.0000x reference)
//
#include <hip/hip_runtime.h>
#include <hip/hip_fp16.h>
#include <math.h>

#define BATCH 8
#define H 480
#define W 640
#define HW (H * W)

// ---- single-launch geometry: all 16 steps fused ----
#define PS 16                 // fused steps (= total)
#define PTX 64                // output tile width
#define PTY 32                // output tile height
#define PRX 96                // region cols = PTX + 2*PS
#define PRY 64                // region rows = PTY + 2*PS
#define PLSTR 98              // LDS row stride: 1 pad | 96 | 1 pad
#define PNT 768               // threads: 96 cols x 8 strips
#define RPT 8                 // rows per thread (PRY / 8)

__device__ __forceinline__ unsigned pk2(float a, float b) {
    unsigned lo = __half_as_ushort(__float2half_rn(a));
    unsigned hi = __half_as_ushort(__float2half_rn(b));
    return lo | (hi << 16);
}
__device__ __forceinline__ float lo2f(unsigned u) {
    return __half2float(__ushort_as_half((unsigned short)(u & 0xffffu)));
}
__device__ __forceinline__ float hi2f(unsigned u) {
    return __half2float(__ushort_as_half((unsigned short)(u >> 16)));
}

// One launch does everything: inline per-region-pixel softmax+mask fold into
// 40 weight VGPRs, then 16 Jacobi steps in double-buffered LDS.
// Lane = region column (stride-1 LDS, conflict-free); 8 rows per thread.
// Rim staleness is harmless by the trapezoid property (margin = PS); out-of-
// image pixels have w=0,bias=0 so they stay exactly 0 (zero-pad semantics).
__global__ __launch_bounds__(PNT) void prop16_kernel(
    const float* __restrict__ guided,   // (B,9,H,W)
    const float* __restrict__ x,        // (B,1,H,W)
    const float* __restrict__ sparse,   // (B,1,H,W)
    float* __restrict__ xout)           // (B,1,H,W)
{
    __shared__ float xs[2][PRY][PLSTR];   // 50,176 B

    const int tid = threadIdx.x;
    const int c  = tid % PRX;            // region col (0..95)
    const int s  = tid / PRX;            // strip (0..7)
    const int r0 = s * RPT;              // first region row of strip
    const int b  = blockIdx.z;
    const int bx0 = blockIdx.x * PTX, by0 = blockIdx.y * PTY;
    const int gx0 = bx0 - PS, gy0 = by0 - PS;
    const size_t ob = (size_t)b * HW;

    // zero the pad columns of BOTH buffers (never written afterwards)
    if (tid < 2 * PRY * 2) {
        const int bf = tid / (PRY * 2), rem = tid % (PRY * 2);
        xs[bf][rem >> 1][(rem & 1) * (PLSTR - 1)] = 0.0f;
    }
    // fill buffer0 interior with x region (zeros outside image)
    for (int i = tid; i < PRY * PRX; i += PNT) {
        const int r = i / PRX, cc = i % PRX;
        const int gy = gy0 + r, gx = gx0 + cc;
        float v = 0.0f;
        if (gy >= 0 && gy < H && gx >= 0 && gx < W)
            v = x[ob + (size_t)gy * W + gx];
        xs[0][r][1 + cc] = v;
    }

    // inline softmax + mask fold for own column pixels -> 40 weight u32
    unsigned q0[RPT], q1[RPT], q2[RPT], q3[RPT], q4[RPT];
    {
        const int gx = gx0 + c;
        const bool xok = (gx >= 0) && (gx < W);
#pragma unroll
        for (int i = 0; i < RPT; ++i) {
            const int gy = gy0 + r0 + i;
            if (xok && gy >= 0 && gy < H) {
                const size_t p = (size_t)gy * W + gx;
                float g[9];
                float m = -INFINITY;
#pragma unroll
                for (int k = 0; k < 9; ++k) {
                    g[k] = guided[((size_t)(b * 9 + k)) * HW + p];
                    m = fmaxf(m, g[k]);
                }
                float ssum = 0.0f;
#pragma unroll
                for (int k = 0; k < 9; ++k) { g[k] = __expf(g[k] - m); ssum += g[k]; }
                const float sv = sparse[ob + p];
                const float mask = (sv > 0.0f) ? 1.0f : 0.0f;
                const float scale = (1.0f - mask) / ssum;
                q0[i] = pk2(g[0] * scale, g[1] * scale);
                q1[i] = pk2(g[2] * scale, g[3] * scale);
                q2[i] = pk2(g[4] * scale, g[5] * scale);
                q3[i] = pk2(g[6] * scale, g[7] * scale);
                q4[i] = pk2(g[8] * scale, mask * x[ob + p]);
            } else {
                q0[i] = 0u; q1[i] = 0u; q2[i] = 0u; q3[i] = 0u; q4[i] = 0u;
            }
        }
    }
    __syncthreads();

    const int rtop = (s == 0) ? 0 : (r0 - 1);                 // clamp at rim
    const int rbot = (r0 + RPT > PRY - 1) ? (PRY - 1) : (r0 + RPT);

    for (int t = 0; t < PS; ++t) {
        const float (*rd)[PLSTR] = xs[t & 1];
        float (*wr)[PLSTR] = xs[(t + 1) & 1];
        // 3-float window sliding down the strip; stride-1 lane addressing
        float t0 = rd[rtop][c], t1 = rd[rtop][c + 1], t2 = rd[rtop][c + 2];
        float m0 = rd[r0][c],   m1 = rd[r0][c + 1],   m2 = rd[r0][c + 2];
#pragma unroll
        for (int i = 0; i < RPT; ++i) {
            const int rb = (i == RPT - 1) ? rbot : (r0 + i + 1);
            const float b0 = rd[rb][c], b1 = rd[rb][c + 1], b2 = rd[rb][c + 2];
            float a = hi2f(q4[i]);                  // bias
            a = fmaf(lo2f(q0[i]), t0, a);
            a = fmaf(hi2f(q0[i]), t1, a);
            a = fmaf(lo2f(q1[i]), t2, a);
            a = fmaf(hi2f(q1[i]), m0, a);
            a = fmaf(lo2f(q2[i]), m1, a);
            a = fmaf(hi2f(q2[i]), m2, a);
            a = fmaf(lo2f(q3[i]), b0, a);
            a = fmaf(hi2f(q3[i]), b1, a);
            a = fmaf(lo2f(q4[i]), b2, a);
            wr[r0 + i][1 + c] = a;
            t0 = m0; t1 = m1; t2 = m2;
            m0 = b0; m1 = b1; m2 = b2;
        }
        __syncthreads();        // wr complete before it becomes rd
    }

    // after 16 steps (even), final values are in buffer 0; write tile out
    for (int i = tid; i < PTX * PTY; i += PNT) {
        const int r = i >> 6, cc = i & 63;
        xout[ob + (size_t)(by0 + r) * W + (bx0 + cc)] =
            xs[0][PS + r][1 + PS + cc];
    }
}

extern "C" void kernel_launch(void* const* d_in, const int* in_sizes, int n_in,
                              void* d_out, int out_size, void* d_ws, size_t ws_size,
                              hipStream_t stream) {
    const float* guided = (const float*)d_in[0];
    const float* x      = (const float*)d_in[1];
    const float* sparse = (const float*)d_in[2];
    float* out = (float*)d_out;

    dim3 blk(PNT, 1, 1);
    dim3 grd(W / PTX, H / PTY, BATCH);   // 10 x 15 x 8 = 1200 blocks
    prop16_kernel<<<grd, blk, 0, stream>>>(guided, x, sparse, out);
}

// Round 8
// 98.036 us; speedup vs baseline: 1.2121x; 1.2121x over previous
//
#include <hip/hip_runtime.h>
#include <hip/hip_fp16.h>
#include <math.h>

#define BATCH 8
#define H 480
#define W 640
#define HW (H * W)

// ---- single-launch geometry: all 16 steps fused ----
#define PS 16                 // fused steps (= total)
#define PTX 96                // output tile width
#define PTY 32                // output tile height
#define PRX 128               // region cols = PTX + 2*PS (= 64 lanes x 2)
#define PRY 64                // region rows = PTY + 2*PS
#define NT 1024               // 16 waves; wave = strip of 4 rows, lane = col-pair
#define RPT 4                 // rows per thread

// DPP wave-wide shifts (GFX9/CDNA): lane i <- lane i-1 (0x138), lane i+1 (0x130).
// Shifted-in lanes take `old` (=0): region col -1 / col 128 read as 0, which
// only feeds rim pixels (trapezoid-stale-safe) or out-of-image pixels (w=0).
__device__ __forceinline__ float dppL(float v) {   // value from lane-1
    return __int_as_float(__builtin_amdgcn_update_dpp(
        0, __float_as_int(v), 0x138, 0xF, 0xF, false));
}
__device__ __forceinline__ float dppR(float v) {   // value from lane+1
    return __int_as_float(__builtin_amdgcn_update_dpp(
        0, __float_as_int(v), 0x130, 0xF, 0xF, false));
}
__device__ __forceinline__ unsigned pk2(float a, float b) {
    unsigned lo = __half_as_ushort(__float2half_rn(a));
    unsigned hi = __half_as_ushort(__float2half_rn(b));
    return lo | (hi << 16);
}
__device__ __forceinline__ float hlo(unsigned u) {
    const __half2 h = __builtin_bit_cast(__half2, u);
    return __half2float(h.x);
}
__device__ __forceinline__ float hhi(unsigned u) {
    const __half2 h = __builtin_bit_cast(__half2, u);
    return __half2float(h.y);
}

// window of one LDS row for this lane's 2 px: {c-1, c, c+1, c+2}
__device__ __forceinline__ float4 ldrow(const float* rowp, int lane) {
    const float2 v = *(const float2*)(rowp + 2 * lane);
    float4 w;
    w.x = dppL(v.y);      // col c-1 = left pair's .y
    w.y = v.x;
    w.z = v.y;
    w.w = dppR(v.x);      // col c+2 = right pair's .x
    return w;
}

__global__ __launch_bounds__(NT) void prop16_kernel(
    const float* __restrict__ guided,   // (B,9,H,W)
    const float* __restrict__ x,        // (B,1,H,W)
    const float* __restrict__ sparse,   // (B,1,H,W)
    float* __restrict__ xout)           // (B,1,H,W)
{
    __shared__ float xs[2][PRY][PRX];   // 65,536 B, no pads (DPP handles +-1 col)

    const int tid  = threadIdx.x;
    const int lane = tid & 63;          // col pair (0..63)
    const int strip = tid >> 6;         // wave id = strip (0..15)
    const int r0 = strip * RPT;
    const int b = blockIdx.z;
    const int bx0 = blockIdx.x * PTX, by0 = blockIdx.y * PTY;
    const int gx0 = bx0 - PS, gy0 = by0 - PS;
    const size_t ob = (size_t)b * HW;

    // ---- fill buf0 with x region (float2 pairs; all-or-nothing since gx even) ----
    {
        const int gx = gx0 + 2 * lane;
        const bool cok = (gx >= 0) && (gx < W);
#pragma unroll
        for (int j = 0; j < 4; ++j) {
            const int r = strip + 16 * j;
            const int gy = gy0 + r;
            float2 v = make_float2(0.f, 0.f);
            if (cok && gy >= 0 && gy < H)
                v = *(const float2*)(x + ob + (size_t)gy * W + gx);
            *(float2*)&xs[0][r][2 * lane] = v;
        }
    }
    __syncthreads();

    // ---- inline softmax + mask fold for own 2x4 px -> 40 weight u32 ----
    unsigned qe0[RPT], qe1[RPT], qe2[RPT], qe3[RPT], qe4[RPT];
    unsigned qo0[RPT], qo1[RPT], qo2[RPT], qo3[RPT], qo4[RPT];
    {
        const int gx = gx0 + 2 * lane;
        const bool cok = (gx >= 0) && (gx < W);
#pragma unroll
        for (int i = 0; i < RPT; ++i) {
            const int r = r0 + i;
            const int gy = gy0 + r;
            if (cok && gy >= 0 && gy < H) {
                const size_t p = (size_t)gy * W + gx;
                float2 g[9];
                float mex = -INFINITY, mey = -INFINITY;
#pragma unroll
                for (int k = 0; k < 9; ++k) {
                    g[k] = *(const float2*)(guided + ((size_t)(b * 9 + k)) * HW + p);
                    mex = fmaxf(mex, g[k].x);
                    mey = fmaxf(mey, g[k].y);
                }
                float se = 0.f, so = 0.f;
#pragma unroll
                for (int k = 0; k < 9; ++k) {
                    g[k].x = __expf(g[k].x - mex); se += g[k].x;
                    g[k].y = __expf(g[k].y - mey); so += g[k].y;
                }
                const float2 sv = *(const float2*)(sparse + ob + p);
                const float maske = (sv.x > 0.f) ? 1.f : 0.f;
                const float masko = (sv.y > 0.f) ? 1.f : 0.f;
                const float sce = (1.f - maske) / se;
                const float sco = (1.f - masko) / so;
                qe0[i] = pk2(g[0].x * sce, g[1].x * sce);
                qe1[i] = pk2(g[2].x * sce, g[3].x * sce);
                qe2[i] = pk2(g[4].x * sce, g[5].x * sce);
                qe3[i] = pk2(g[6].x * sce, g[7].x * sce);
                qe4[i] = pk2(g[8].x * sce, maske * xs[0][r][2 * lane]);
                qo0[i] = pk2(g[0].y * sco, g[1].y * sco);
                qo1[i] = pk2(g[2].y * sco, g[3].y * sco);
                qo2[i] = pk2(g[4].y * sco, g[5].y * sco);
                qo3[i] = pk2(g[6].y * sco, g[7].y * sco);
                qo4[i] = pk2(g[8].y * sco, masko * xs[0][r][2 * lane + 1]);
            } else {
                qe0[i] = qe1[i] = qe2[i] = qe3[i] = qe4[i] = 0u;
                qo0[i] = qo1[i] = qo2[i] = qo3[i] = qo4[i] = 0u;
            }
        }
    }

    const int rm1 = (strip == 0) ? 0 : (r0 - 1);          // clamped rim rows
    const int rb3 = (strip == 15) ? (PRY - 1) : (r0 + RPT);

    // ---- 16 Jacobi steps, double-buffered, 1 barrier/step ----
    for (int t = 0; t < PS; ++t) {
        const float (*rd)[PRX] = xs[t & 1];
        float (*wr)[PRX] = xs[(t + 1) & 1];

        float4 T = ldrow(&rd[rm1][0], lane);
        float4 M = ldrow(&rd[r0][0], lane);
#pragma unroll
        for (int i = 0; i < RPT; ++i) {
            const int rb = (i == RPT - 1) ? rb3 : (r0 + i + 1);
            const float4 Bw = ldrow(&rd[rb][0], lane);
            // even px (col 2*lane): window cols {x,y,z} of each row
            float ae = hhi(qe4[i]);
            ae = fmaf(hlo(qe0[i]), T.x, ae);
            ae = fmaf(hhi(qe0[i]), T.y, ae);
            ae = fmaf(hlo(qe1[i]), T.z, ae);
            ae = fmaf(hhi(qe1[i]), M.x, ae);
            ae = fmaf(hlo(qe2[i]), M.y, ae);
            ae = fmaf(hhi(qe2[i]), M.z, ae);
            ae = fmaf(hlo(qe3[i]), Bw.x, ae);
            ae = fmaf(hhi(qe3[i]), Bw.y, ae);
            ae = fmaf(hlo(qe4[i]), Bw.z, ae);
            // odd px (col 2*lane+1): window cols {y,z,w}
            float ao = hhi(qo4[i]);
            ao = fmaf(hlo(qo0[i]), T.y, ao);
            ao = fmaf(hhi(qo0[i]), T.z, ao);
            ao = fmaf(hlo(qo1[i]), T.w, ao);
            ao = fmaf(hhi(qo1[i]), M.y, ao);
            ao = fmaf(hlo(qo2[i]), M.z, ao);
            ao = fmaf(hhi(qo2[i]), M.w, ao);
            ao = fmaf(hlo(qo3[i]), Bw.y, ao);
            ao = fmaf(hhi(qo3[i]), Bw.z, ao);
            ao = fmaf(hlo(qo4[i]), Bw.w, ao);
            *(float2*)&wr[r0 + i][2 * lane] = make_float2(ae, ao);
            T = M; M = Bw;
        }
        __syncthreads();      // wr complete before it becomes rd
    }

    // ---- after 16 steps final values in buf0; write tile (coalesced) ----
    for (int i = tid; i < PTX * PTY; i += NT) {
        const int r = i / PTX, cc = i - r * PTX;
        const int gx = bx0 + cc;
        if (gx < W)
            xout[ob + (size_t)(by0 + r) * W + gx] = xs[0][PS + r][PS + cc];
    }
}

extern "C" void kernel_launch(void* const* d_in, const int* in_sizes, int n_in,
                              void* d_out, int out_size, void* d_ws, size_t ws_size,
                              hipStream_t stream) {
    const float* guided = (const float*)d_in[0];
    const float* x      = (const float*)d_in[1];
    const float* sparse = (const float*)d_in[2];
    float* out = (float*)d_out;

    dim3 blk(NT, 1, 1);
    dim3 grd((W + PTX - 1) / PTX, H / PTY, BATCH);   // 7 x 15 x 8 = 840 blocks
    prop16_kernel<<<grd, blk, 0, stream>>>(guided, x, sparse, out);
}